// Round 4
// baseline (299.150 us; speedup 1.0000x reference)
//
#include <hip/hip_runtime.h>

#define D 128

typedef __attribute__((ext_vector_type(8))) short short8;
typedef __attribute__((ext_vector_type(4))) float f32x4;

// fp32 -> bf16 bits, round-to-nearest-even
__device__ inline unsigned int f2bf_bits(float f) {
    unsigned int u = __float_as_uint(f);
    return (u + 0x7FFFu + ((u >> 16) & 1u)) >> 16;
}

__device__ inline float bfhi(unsigned int u) { return __uint_as_float(u << 16); }
__device__ inline float bflo(unsigned int u) { return __uint_as_float(u & 0xffff0000u); }

// ---------------- fused prep: x -> bf16 hi/lo (row-major), weight pack, zero chist/csrpad ----
__global__ __launch_bounds__(256) void prep_kernel(
    const float* __restrict__ x,
    const float* __restrict__ W1l, const float* __restrict__ W1r,
    const float* __restrict__ W2l, const float* __restrict__ W2r,
    unsigned short* __restrict__ xbf, unsigned short* __restrict__ xlo,
    unsigned short* __restrict__ h1, unsigned short* __restrict__ l1,
    unsigned short* __restrict__ h2, unsigned short* __restrict__ l2,
    int n4, int ncast, int* __restrict__ chist, int* __restrict__ csrpad)
{
    const int b = blockIdx.x;
    const int t = threadIdx.x;
    if (b < ncast) {
        int i = b * 256 + t;
        if (i >= n4) return;
        f32x4 v = *(const f32x4*)(x + (size_t)i * 4);
        ushort4 oh, ol;
        {
            unsigned int h; float hf;
            h = f2bf_bits(v.x); hf = __uint_as_float(h << 16);
            oh.x = (unsigned short)h; ol.x = (unsigned short)f2bf_bits(v.x - hf);
            h = f2bf_bits(v.y); hf = __uint_as_float(h << 16);
            oh.y = (unsigned short)h; ol.y = (unsigned short)f2bf_bits(v.y - hf);
            h = f2bf_bits(v.z); hf = __uint_as_float(h << 16);
            oh.z = (unsigned short)h; ol.z = (unsigned short)f2bf_bits(v.z - hf);
            h = f2bf_bits(v.w); hf = __uint_as_float(h << 16);
            oh.w = (unsigned short)h; ol.w = (unsigned short)f2bf_bits(v.w - hf);
        }
        *(ushort4*)(xbf + (size_t)i * 4) = oh;
        *(ushort4*)(xlo + (size_t)i * 4) = ol;
    } else if (b < ncast + 256) {
        // weight pack: B-frag order + bf16 hi/lo split
        int gidx = (b - ncast) * 256 + t;   // 0..65535
        int sel = gidx >> 15;
        int idx = gidx & 32767;
        int tt = idx >> 12;
        int ks = (idx >> 9) & 7;
        int lane = (idx >> 3) & 63;
        int j = idx & 7;
        int qq = lane >> 4, r16 = lane & 15;
        int k = ks * 32 + qq * 8 + j;
        int c = tt * 16 + r16;
        const float* Wl = sel ? W2l : W1l;
        const float* Wr = sel ? W2r : W1r;
        float v = (k < 128) ? Wl[k * 128 + c] : Wr[(k - 128) * 128 + c];
        unsigned int h = f2bf_bits(v);
        float hf = __uint_as_float(h << 16);
        unsigned int l = f2bf_bits(v - hf);
        (sel ? h2 : h1)[idx] = (unsigned short)h;
        (sel ? l2 : l1)[idx] = (unsigned short)l;
    } else {
        chist[t] = 0;
        if (t < 16) csrpad[t] = 0;
    }
}

// ---------------- pass A: coarse histogram (bucket = dst>>8) via LDS ----------------
__global__ __launch_bounds__(256) void coarse_count_kernel(const int* __restrict__ dst,
                                                           int* __restrict__ chist, int E) {
    __shared__ int h[256];
    h[threadIdx.x] = 0;
    __syncthreads();
    const int stride = gridDim.x * 256;
    for (int e = blockIdx.x * 256 + threadIdx.x; e < E; e += stride)
        atomicAdd(&h[dst[e] >> 8], 1);
    __syncthreads();
    int v = h[threadIdx.x];
    if (v) atomicAdd(&chist[threadIdx.x], v);
}

// ---------------- pass B: scan 256 bucket counts -> cbase (excl, 257) + gcur ----------------
__global__ __launch_bounds__(256) void scan256_kernel(const int* __restrict__ chist,
                                                      int* __restrict__ cbase,
                                                      int* __restrict__ gcur) {
    __shared__ int wsum[4];
    const int t = threadIdx.x, lane = t & 63, wv = t >> 6;
    int v = chist[t];
    int s = v;
#pragma unroll
    for (int o = 1; o < 64; o <<= 1) {
        int u = __shfl_up(s, o, 64);
        if (lane >= o) s += u;
    }
    if (lane == 63) wsum[wv] = s;
    __syncthreads();
    int add = 0;
    for (int w = 0; w < wv; ++w) add += wsum[w];
    cbase[t + 1] = s + add;
    if (t == 0) cbase[0] = 0;
    gcur[t] = s + add - v;
}

// ---------------- pass C: coarse multisplit scatter ----------------
#define CCHUNK 4096
__global__ __launch_bounds__(256) void coarse_scatter_kernel(
    const int* __restrict__ src, const int* __restrict__ dst,
    int* __restrict__ gcur, unsigned int* __restrict__ centries, int E)
{
    __shared__ int h[256];
    __shared__ int base[256];
    __shared__ unsigned int stage[CCHUNK];
    const int t = threadIdx.x;
    const int e0 = blockIdx.x * CCHUNK;
    h[t] = 0;
    __syncthreads();
#pragma unroll
    for (int i = 0; i < 16; ++i) {
        int e = e0 + i * 256 + t;
        unsigned int u = 0xFFFFFFFFu;
        if (e < E) {
            int d = dst[e];
            int s = src[e];
            int b = d >> 8;
            u = ((unsigned)b << 24) | ((unsigned)s << 8) | (unsigned)(d & 255);
            atomicAdd(&h[b], 1);
        }
        stage[i * 256 + t] = u;
    }
    __syncthreads();
    base[t] = atomicAdd(&gcur[t], h[t]);
    __syncthreads();
    h[t] = 0;
    __syncthreads();
#pragma unroll
    for (int i = 0; i < 16; ++i) {
        unsigned int u = stage[i * 256 + t];
        if (u != 0xFFFFFFFFu) {
            int b = u >> 24;
            int r = atomicAdd(&h[b], 1);
            centries[base[b] + r] = u & 0x00FFFFFFu;
        }
    }
}

// ---------------- pass D: fine bucket (one block per coarse bucket) ----------------
#define DCAP 8192
__global__ __launch_bounds__(256) void fine_bucket_kernel(
    const unsigned int* __restrict__ centries,
    const int* __restrict__ cbase,
    int* __restrict__ offo, int* __restrict__ csr, int N, int E)
{
    __shared__ int h[256], ex[256], wsum[4];
    __shared__ int stg[DCAP];
    const int t = threadIdx.x, lane = t & 63, wv = t >> 6;
    const int b = blockIdx.x;
    const int s0 = cbase[b];
    const int cnt = cbase[b + 1] - s0;
    h[t] = 0;
    __syncthreads();
    for (int i = t; i < cnt; i += 256)
        atomicAdd(&h[centries[s0 + i] & 255], 1);
    __syncthreads();
    int v = h[t], s = v;
#pragma unroll
    for (int o = 1; o < 64; o <<= 1) {
        int u = __shfl_up(s, o, 64);
        if (lane >= o) s += u;
    }
    if (lane == 63) wsum[wv] = s;
    __syncthreads();
    int add = 0;
    for (int w = 0; w < wv; ++w) add += wsum[w];
    const int exc = s + add - v;
    ex[t] = exc;
    const int dg = b * 256 + t;
    if (dg < N) offo[dg] = s0 + exc;
    if (b == 0 && t == 0) offo[N] = E;
    h[t] = 0;
    __syncthreads();
    if (cnt <= DCAP) {
        for (int i = t; i < cnt; i += 256) {
            unsigned int u = centries[s0 + i];
            int dl = u & 255;
            int r = atomicAdd(&h[dl], 1);
            stg[ex[dl] + r] = (int)(u >> 8);
        }
        __syncthreads();
        for (int i = t; i < cnt; i += 256)
            csr[s0 + i] = stg[i];
    } else {
        for (int i = t; i < cnt; i += 256) {
            unsigned int u = centries[s0 + i];
            int dl = u & 255;
            int r = atomicAdd(&h[dl], 1);
            csr[s0 + ex[dl] + r] = (int)(u >> 8);
        }
    }
}

// ---------------- fused gather-mean + MFMA GEMM (1 wave = 1 tile) ----------------
// One 64-lane wave per block owns a 16-node tile: waves retire independently,
// so degree variance doesn't strand block resources (fixes 14% occupancy).
// Lane (q=lane>>4, r16=lane&15) gathers channels [ks*32+q*8, +8) of node
// r16's neighbors (ks=0..3) into its A-frag accumulator, splits to bf16
// hi/lo in-register, then runs the depth-2 B-double-buffered 24-MFMA loop
// (self rows feed stages ks=4..7). Math identical to round 3.
__device__ inline void loadb8(const unsigned short* __restrict__ bh,
                              const unsigned short* __restrict__ bl,
                              int ks, short8* BH, short8* BL) {
    const unsigned short* p = bh + (size_t)ks * 512;
    const unsigned short* q = bl + (size_t)ks * 512;
#pragma unroll
    for (int t = 0; t < 8; ++t) {
        BH[t] = *(const short8*)(p + (size_t)t * 4096);
        BL[t] = *(const short8*)(q + (size_t)t * 4096);
    }
}

__device__ inline void mfma24(const short8& AH, const short8& AL,
                              const short8* BH, const short8* BL, f32x4* acc) {
#pragma unroll
    for (int t = 0; t < 8; ++t) {
        acc[t] = __builtin_amdgcn_mfma_f32_16x16x32_bf16(AH, BH[t], acc[t], 0, 0, 0);
        acc[t] = __builtin_amdgcn_mfma_f32_16x16x32_bf16(AL, BH[t], acc[t], 0, 0, 0);
        acc[t] = __builtin_amdgcn_mfma_f32_16x16x32_bf16(AH, BL[t], acc[t], 0, 0, 0);
    }
}

__global__ __launch_bounds__(64, 3) void fused_sage_kernel(
    const unsigned short* __restrict__ featbf,    // gather table (bf16 hi), row-major
    const int* __restrict__ off,
    const int* __restrict__ csr,
    const unsigned short* __restrict__ self_hi,   // row-major bf16 (hi)
    const unsigned short* __restrict__ self_lo,   // row-major bf16 (lo)
    const unsigned short* __restrict__ wpk_hi,
    const unsigned short* __restrict__ wpk_lo,
    const float* __restrict__ bias,
    unsigned short* __restrict__ out_hi,          // row-major bf16
    unsigned short* __restrict__ out_lo,          // nullable (layer-1 h lo)
    int do_relu)
{
    const int lane = threadIdx.x;                 // 0..63
    const int tile = blockIdx.x;
    const int q = lane >> 4, r16 = lane & 15;
    const int n0w = tile * 16;
    const int node = n0w + r16;

    const unsigned short* bh = wpk_hi + lane * 8;
    const unsigned short* bl = wpk_lo + lane * 8;

    // preload B stage 0 (lands during the gather phase)
    short8 BH0[8], BL0[8], BH1[8], BL1[8];
    loadb8(bh, bl, 0, BH0, BL0);

    // ---- gather phase ----
    const int start = off[node];
    const int end   = off[node + 1];
    const unsigned short* fb = featbf + q * 8;    // + idx*D + seg*32
    float ga[4][8];
#pragma unroll
    for (int k = 0; k < 4; ++k)
#pragma unroll
        for (int c = 0; c < 8; ++c) ga[k][c] = 0.f;

#define ACCUM(rv, k)                                                     \
    { ga[k][0] += bfhi(rv.x); ga[k][1] += bflo(rv.x);                    \
      ga[k][2] += bfhi(rv.y); ga[k][3] += bflo(rv.y);                    \
      ga[k][4] += bfhi(rv.z); ga[k][5] += bflo(rv.z);                    \
      ga[k][6] += bfhi(rv.w); ga[k][7] += bflo(rv.w); }

    const uint4 zero4 = {0u, 0u, 0u, 0u};
    if (start < end) {
        int4 ix = *(const int4*)(csr + start);
        for (int e = start; e < end; e += 4) {
            // prefetch next batch's indices (padded/overshoot-safe: reads
            // neighbor-node edges, used only if e+4 < end)
            int4 ixn = *(const int4*)(csr + e + 4);
            const unsigned short* p0 = fb + (size_t)ix.x * D;
            const unsigned short* p1 = fb + (size_t)ix.y * D;
            const unsigned short* p2 = fb + (size_t)ix.z * D;
            const unsigned short* p3 = fb + (size_t)ix.w * D;
            uint4 r00 = *(const uint4*)(p0);
            uint4 r01 = *(const uint4*)(p0 + 32);
            uint4 r02 = *(const uint4*)(p0 + 64);
            uint4 r03 = *(const uint4*)(p0 + 96);
            uint4 r10 = *(const uint4*)(p1);
            uint4 r11 = *(const uint4*)(p1 + 32);
            uint4 r12 = *(const uint4*)(p1 + 64);
            uint4 r13 = *(const uint4*)(p1 + 96);
            uint4 r20 = *(const uint4*)(p2);
            uint4 r21 = *(const uint4*)(p2 + 32);
            uint4 r22 = *(const uint4*)(p2 + 64);
            uint4 r23 = *(const uint4*)(p2 + 96);
            uint4 r30 = *(const uint4*)(p3);
            uint4 r31 = *(const uint4*)(p3 + 32);
            uint4 r32 = *(const uint4*)(p3 + 64);
            uint4 r33 = *(const uint4*)(p3 + 96);
            if (e + 1 >= end) { r10 = zero4; r11 = zero4; r12 = zero4; r13 = zero4; }
            if (e + 2 >= end) { r20 = zero4; r21 = zero4; r22 = zero4; r23 = zero4; }
            if (e + 3 >= end) { r30 = zero4; r31 = zero4; r32 = zero4; r33 = zero4; }
            ACCUM(r00, 0) ACCUM(r01, 1) ACCUM(r02, 2) ACCUM(r03, 3)
            ACCUM(r10, 0) ACCUM(r11, 1) ACCUM(r12, 2) ACCUM(r13, 3)
            ACCUM(r20, 0) ACCUM(r21, 1) ACCUM(r22, 2) ACCUM(r23, 3)
            ACCUM(r30, 0) ACCUM(r31, 1) ACCUM(r32, 2) ACCUM(r33, 3)
            ix = ixn;
        }
    }
#undef ACCUM

    // mean + bf16 hi/lo split (identical math to previous rounds)
    const float dinv = 1.0f / (float)max(end - start, 1);
    short8 AH[4], AL[4];
#pragma unroll
    for (int k = 0; k < 4; ++k) {
#pragma unroll
        for (int c = 0; c < 8; ++c) {
            float v = ga[k][c] * dinv;
            unsigned int hbits = f2bf_bits(v);
            AH[k][c] = (short)hbits;
            AL[k][c] = (short)f2bf_bits(v - __uint_as_float(hbits << 16));
        }
    }

    // ---- MFMA stage loop (depth-2 B double-buffer) ----
    f32x4 acc8[8];
#pragma unroll
    for (int t = 0; t < 8; ++t) acc8[t] = (f32x4){0.f, 0.f, 0.f, 0.f};

    const unsigned short* sph = self_hi + (size_t)node * D + q * 8;
    const unsigned short* spl = self_lo + (size_t)node * D + q * 8;

    short8 SH0, SL0, SH1, SL1;
    loadb8(bh, bl, 1, BH1, BL1);
    SH0 = *(const short8*)(sph);          // self ks=4
    SL0 = *(const short8*)(spl);
    mfma24(AH[0], AL[0], BH0, BL0, acc8);
    loadb8(bh, bl, 2, BH0, BL0);
    SH1 = *(const short8*)(sph + 32);     // self ks=5
    SL1 = *(const short8*)(spl + 32);
    mfma24(AH[1], AL[1], BH1, BL1, acc8);
    loadb8(bh, bl, 3, BH1, BL1);
    mfma24(AH[2], AL[2], BH0, BL0, acc8);
    loadb8(bh, bl, 4, BH0, BL0);
    mfma24(AH[3], AL[3], BH1, BL1, acc8);
    loadb8(bh, bl, 5, BH1, BL1);
    mfma24(SH0, SL0, BH0, BL0, acc8);
    loadb8(bh, bl, 6, BH0, BL0);
    SH0 = *(const short8*)(sph + 64);     // self ks=6
    SL0 = *(const short8*)(spl + 64);
    mfma24(SH1, SL1, BH1, BL1, acc8);
    loadb8(bh, bl, 7, BH1, BL1);
    SH1 = *(const short8*)(sph + 96);     // self ks=7
    SL1 = *(const short8*)(spl + 96);
    mfma24(SH0, SL0, BH0, BL0, acc8);
    mfma24(SH1, SL1, BH1, BL1, acc8);

    // epilogue: C/D layout col=lane&15, row=quad*4+reg; row-major bf16 out
#pragma unroll
    for (int t = 0; t < 8; ++t) {
        const float bv = bias[t * 16 + r16];
#pragma unroll
        for (int r = 0; r < 4; ++r) {
            float vv = acc8[t][r] + bv;
            if (do_relu) vv = fmaxf(vv, 0.f);
            const size_t o = (size_t)(n0w + q * 4 + r) * D + t * 16 + r16;
            unsigned int h = f2bf_bits(vv);
            out_hi[o] = (unsigned short)h;
            if (out_lo) {
                float hf = __uint_as_float(h << 16);
                out_lo[o] = (unsigned short)f2bf_bits(vv - hf);
            }
        }
    }
}

// ---------------- edge dot-product decode (bf16 z rows) ----------------
// 32 lanes per edge, 8 B loads, reduce depth 5.
__global__ __launch_bounds__(256) void pred_kernel(const unsigned short* __restrict__ zbf,
                                                   const int* __restrict__ ps,
                                                   const int* __restrict__ pd,
                                                   float* __restrict__ out, int EP) {
    int idx = blockIdx.x * blockDim.x + threadIdx.x;
    int e = idx >> 5;
    if (e >= EP) return;
    int l = idx & 31;
    const unsigned short* fb = zbf + (size_t)l * 4;
    uint2 ra = *(const uint2*)(fb + (size_t)ps[e] * D);
    uint2 rb = *(const uint2*)(fb + (size_t)pd[e] * D);
    float p = __uint_as_float(ra.x << 16)         * __uint_as_float(rb.x << 16)
            + __uint_as_float(ra.x & 0xffff0000u) * __uint_as_float(rb.x & 0xffff0000u)
            + __uint_as_float(ra.y << 16)         * __uint_as_float(rb.y << 16)
            + __uint_as_float(ra.y & 0xffff0000u) * __uint_as_float(rb.y & 0xffff0000u);
#pragma unroll
    for (int off = 16; off > 0; off >>= 1) p += __shfl_xor(p, off, 32);
    if (l == 0) out[e] = p;
}

extern "C" void kernel_launch(void* const* d_in, const int* in_sizes, int n_in,
                              void* d_out, int out_size, void* d_ws, size_t ws_size,
                              hipStream_t stream) {
    const float* x   = (const float*)d_in[0];
    const float* W1l = (const float*)d_in[1];
    const float* b1  = (const float*)d_in[2];
    const float* W1r = (const float*)d_in[3];
    const float* W2l = (const float*)d_in[4];
    const float* b2  = (const float*)d_in[5];
    const float* W2r = (const float*)d_in[6];
    const int* edge_index = (const int*)d_in[7];
    const int* pred_edges = (const int*)d_in[8];
    float* out = (float*)d_out;

    const int N  = in_sizes[0] / D;   // 50000
    const int E  = in_sizes[7] / 2;   // 800000
    const int EP = in_sizes[8] / 2;   // 200000

    const int* src = edge_index;
    const int* dst = edge_index + E;
    const int* ps  = pred_edges;
    const int* pd  = pred_edges + EP;

    // workspace layout
    int* chist   = (int*)d_ws;                 // 256
    int* cbase   = chist + 256;                // 257 (pad 272)
    int* gcur    = cbase + 272;                // 256
    int* off     = gcur + 256;                 // N+1 (pad 50016)
    unsigned int* centries = (unsigned int*)(off + 50016);  // E
    int* csr     = (int*)(centries + E);       // E + 16 pad
    unsigned short* w1_hi = (unsigned short*)(csr + E + 16);
    unsigned short* w1_lo = w1_hi + 32768;
    unsigned short* w2_hi = w1_lo + 32768;
    unsigned short* w2_lo = w2_hi + 32768;
    unsigned short* xbf   = w2_lo + 32768;          // N*D bf16 (x hi)
    unsigned short* xlo   = xbf + (size_t)N * D;    // N*D bf16 (x lo)
    unsigned short* hbf   = xlo + (size_t)N * D;    // N*D bf16 (h hi)
    unsigned short* hlo   = hbf + (size_t)N * D;    // N*D bf16 (h lo)
    unsigned short* zbf   = hlo + (size_t)N * D;    // N*D bf16 (z)

    const int n4 = N * D / 4;
    const int ncast = (n4 + 255) / 256;             // 6250
    const int ntiles = N / 16;                      // 3125
    const int nbC = (E + CCHUNK - 1) / CCHUNK;      // 196
    const int nbD = (N + 255) / 256;                // 196
    const int nblk_pred = (EP * 32 + 255) / 256;    // 25000

    // fused prep: x hi/lo cast + weight pack + zero chist & csr pad
    prep_kernel<<<ncast + 257, 256, 0, stream>>>(x, W1l, W1r, W2l, W2r,
                                                 xbf, xlo, w1_hi, w1_lo, w2_hi, w2_lo,
                                                 n4, ncast, chist, csr + E);

    // CSR build: coarse count -> scan -> coarse multisplit -> fine bucket
    coarse_count_kernel<<<256, 256, 0, stream>>>(dst, chist, E);
    scan256_kernel<<<1, 256, 0, stream>>>(chist, cbase, gcur);
    coarse_scatter_kernel<<<nbC, 256, 0, stream>>>(src, dst, gcur, centries, E);
    fine_bucket_kernel<<<nbD, 256, 0, stream>>>(centries, cbase, off, csr, N, E);

    // layer 1: h = relu(mean(x)@W1l + x@W1r + b1) -> hbf/hlo
    fused_sage_kernel<<<ntiles, 64, 0, stream>>>(xbf, off, csr, xbf, xlo,
                                                 w1_hi, w1_lo, b1, hbf, hlo, 1);
    // layer 2: z = mean(h)@W2l + h@W2r + b2 -> zbf
    fused_sage_kernel<<<ntiles, 64, 0, stream>>>(hbf, off, csr, hbf, hlo,
                                                 w2_hi, w2_lo, b2, zbf,
                                                 (unsigned short*)nullptr, 0);
    // decode from bf16 z
    pred_kernel<<<nblk_pred, 256, 0, stream>>>(zbf, ps, pd, out, EP);
}

// Round 5
// 247.315 us; speedup vs baseline: 1.2096x; 1.2096x over previous
//
#include <hip/hip_runtime.h>

#define D 128

typedef __attribute__((ext_vector_type(8))) short short8;
typedef __attribute__((ext_vector_type(4))) float f32x4;

// fp32 -> bf16 bits, round-to-nearest-even
__device__ inline unsigned int f2bf_bits(float f) {
    unsigned int u = __float_as_uint(f);
    return (u + 0x7FFFu + ((u >> 16) & 1u)) >> 16;
}

__device__ inline float bfhi(unsigned int u) { return __uint_as_float(u << 16); }
__device__ inline float bflo(unsigned int u) { return __uint_as_float(u & 0xffff0000u); }

// ---------------- fused prep: x -> bf16 hi/lo (row-major), weight pack, zero chist/csrpad ----
__global__ __launch_bounds__(256) void prep_kernel(
    const float* __restrict__ x,
    const float* __restrict__ W1l, const float* __restrict__ W1r,
    const float* __restrict__ W2l, const float* __restrict__ W2r,
    unsigned short* __restrict__ xbf, unsigned short* __restrict__ xlo,
    unsigned short* __restrict__ h1, unsigned short* __restrict__ l1,
    unsigned short* __restrict__ h2, unsigned short* __restrict__ l2,
    int n4, int ncast, int* __restrict__ chist, int* __restrict__ csrpad)
{
    const int b = blockIdx.x;
    const int t = threadIdx.x;
    if (b < ncast) {
        int i = b * 256 + t;
        if (i >= n4) return;
        f32x4 v = *(const f32x4*)(x + (size_t)i * 4);
        ushort4 oh, ol;
        {
            unsigned int h; float hf;
            h = f2bf_bits(v.x); hf = __uint_as_float(h << 16);
            oh.x = (unsigned short)h; ol.x = (unsigned short)f2bf_bits(v.x - hf);
            h = f2bf_bits(v.y); hf = __uint_as_float(h << 16);
            oh.y = (unsigned short)h; ol.y = (unsigned short)f2bf_bits(v.y - hf);
            h = f2bf_bits(v.z); hf = __uint_as_float(h << 16);
            oh.z = (unsigned short)h; ol.z = (unsigned short)f2bf_bits(v.z - hf);
            h = f2bf_bits(v.w); hf = __uint_as_float(h << 16);
            oh.w = (unsigned short)h; ol.w = (unsigned short)f2bf_bits(v.w - hf);
        }
        *(ushort4*)(xbf + (size_t)i * 4) = oh;
        *(ushort4*)(xlo + (size_t)i * 4) = ol;
    } else if (b < ncast + 256) {
        // weight pack: B-frag order + bf16 hi/lo split
        int gidx = (b - ncast) * 256 + t;   // 0..65535
        int sel = gidx >> 15;
        int idx = gidx & 32767;
        int tt = idx >> 12;
        int ks = (idx >> 9) & 7;
        int lane = (idx >> 3) & 63;
        int j = idx & 7;
        int qq = lane >> 4, r16 = lane & 15;
        int k = ks * 32 + qq * 8 + j;
        int c = tt * 16 + r16;
        const float* Wl = sel ? W2l : W1l;
        const float* Wr = sel ? W2r : W1r;
        float v = (k < 128) ? Wl[k * 128 + c] : Wr[(k - 128) * 128 + c];
        unsigned int h = f2bf_bits(v);
        float hf = __uint_as_float(h << 16);
        unsigned int l = f2bf_bits(v - hf);
        (sel ? h2 : h1)[idx] = (unsigned short)h;
        (sel ? l2 : l1)[idx] = (unsigned short)l;
    } else {
        chist[t] = 0;
        if (t < 16) csrpad[t] = 0;
    }
}

// ---------------- pass A: coarse histogram (bucket = dst>>8) via LDS ----------------
__global__ __launch_bounds__(256) void coarse_count_kernel(const int* __restrict__ dst,
                                                           int* __restrict__ chist, int E) {
    __shared__ int h[256];
    h[threadIdx.x] = 0;
    __syncthreads();
    const int stride = gridDim.x * 256;
    for (int e = blockIdx.x * 256 + threadIdx.x; e < E; e += stride)
        atomicAdd(&h[dst[e] >> 8], 1);
    __syncthreads();
    int v = h[threadIdx.x];
    if (v) atomicAdd(&chist[threadIdx.x], v);
}

// ---------------- pass B: scan 256 bucket counts -> cbase (excl, 257) + gcur ----------------
__global__ __launch_bounds__(256) void scan256_kernel(const int* __restrict__ chist,
                                                      int* __restrict__ cbase,
                                                      int* __restrict__ gcur) {
    __shared__ int wsum[4];
    const int t = threadIdx.x, lane = t & 63, wv = t >> 6;
    int v = chist[t];
    int s = v;
#pragma unroll
    for (int o = 1; o < 64; o <<= 1) {
        int u = __shfl_up(s, o, 64);
        if (lane >= o) s += u;
    }
    if (lane == 63) wsum[wv] = s;
    __syncthreads();
    int add = 0;
    for (int w = 0; w < wv; ++w) add += wsum[w];
    cbase[t + 1] = s + add;
    if (t == 0) cbase[0] = 0;
    gcur[t] = s + add - v;
}

// ---------------- pass C: coarse multisplit scatter ----------------
#define CCHUNK 4096
__global__ __launch_bounds__(256) void coarse_scatter_kernel(
    const int* __restrict__ src, const int* __restrict__ dst,
    int* __restrict__ gcur, unsigned int* __restrict__ centries, int E)
{
    __shared__ int h[256];
    __shared__ int base[256];
    __shared__ unsigned int stage[CCHUNK];
    const int t = threadIdx.x;
    const int e0 = blockIdx.x * CCHUNK;
    h[t] = 0;
    __syncthreads();
#pragma unroll
    for (int i = 0; i < 16; ++i) {
        int e = e0 + i * 256 + t;
        unsigned int u = 0xFFFFFFFFu;
        if (e < E) {
            int d = dst[e];
            int s = src[e];
            int b = d >> 8;
            u = ((unsigned)b << 24) | ((unsigned)s << 8) | (unsigned)(d & 255);
            atomicAdd(&h[b], 1);
        }
        stage[i * 256 + t] = u;
    }
    __syncthreads();
    base[t] = atomicAdd(&gcur[t], h[t]);
    __syncthreads();
    h[t] = 0;
    __syncthreads();
#pragma unroll
    for (int i = 0; i < 16; ++i) {
        unsigned int u = stage[i * 256 + t];
        if (u != 0xFFFFFFFFu) {
            int b = u >> 24;
            int r = atomicAdd(&h[b], 1);
            centries[base[b] + r] = u & 0x00FFFFFFu;
        }
    }
}

// ---------------- pass D: fine bucket (one block per coarse bucket) ----------------
#define DCAP 8192
__global__ __launch_bounds__(256) void fine_bucket_kernel(
    const unsigned int* __restrict__ centries,
    const int* __restrict__ cbase,
    int* __restrict__ offo, int* __restrict__ csr, int N, int E)
{
    __shared__ int h[256], ex[256], wsum[4];
    __shared__ int stg[DCAP];
    const int t = threadIdx.x, lane = t & 63, wv = t >> 6;
    const int b = blockIdx.x;
    const int s0 = cbase[b];
    const int cnt = cbase[b + 1] - s0;
    h[t] = 0;
    __syncthreads();
    for (int i = t; i < cnt; i += 256)
        atomicAdd(&h[centries[s0 + i] & 255], 1);
    __syncthreads();
    int v = h[t], s = v;
#pragma unroll
    for (int o = 1; o < 64; o <<= 1) {
        int u = __shfl_up(s, o, 64);
        if (lane >= o) s += u;
    }
    if (lane == 63) wsum[wv] = s;
    __syncthreads();
    int add = 0;
    for (int w = 0; w < wv; ++w) add += wsum[w];
    const int exc = s + add - v;
    ex[t] = exc;
    const int dg = b * 256 + t;
    if (dg < N) offo[dg] = s0 + exc;
    if (b == 0 && t == 0) offo[N] = E;
    h[t] = 0;
    __syncthreads();
    if (cnt <= DCAP) {
        for (int i = t; i < cnt; i += 256) {
            unsigned int u = centries[s0 + i];
            int dl = u & 255;
            int r = atomicAdd(&h[dl], 1);
            stg[ex[dl] + r] = (int)(u >> 8);
        }
        __syncthreads();
        for (int i = t; i < cnt; i += 256)
            csr[s0 + i] = stg[i];
    } else {
        for (int i = t; i < cnt; i += 256) {
            unsigned int u = centries[s0 + i];
            int dl = u & 255;
            int r = atomicAdd(&h[dl], 1);
            csr[s0 + ex[dl] + r] = (int)(u >> 8);
        }
    }
}

// ---------------- fused gather-mean + MFMA GEMM (4 waves per tile) ----------------
// Block = 256 threads = 4 waves, one 16-node tile. Gather: wave w covers
// channels [w*32, w*32+32): lane (gn=l>>2, q2=l&3) accumulates 8 channels of
// node gn (one uint4/edge, depth-2 pipelined). All 4 waves iterate the SAME
// edge lists -> no straggler tail. A-frags exchanged via LDS; wave w then
// computes output col-blocks t=2w,2w+1 (48 MFMAs; per-output accumulation
// order identical to previous rounds -> bit-identical results). Epilogue
// stages the tile in LDS and streams coalesced 16B/thread (kills the HBM
// read-modify-write amplification of scattered 2B stores).
__global__ __launch_bounds__(256, 4) void fused_sage_kernel(
    const unsigned short* __restrict__ featbf,    // gather table (bf16 hi), row-major
    const int* __restrict__ off,
    const int* __restrict__ csr,
    const unsigned short* __restrict__ self_hi,   // row-major bf16 (hi)
    const unsigned short* __restrict__ self_lo,   // row-major bf16 (lo)
    const unsigned short* __restrict__ wpk_hi,
    const unsigned short* __restrict__ wpk_lo,
    const float* __restrict__ bias,
    unsigned short* __restrict__ out_hi,          // row-major bf16
    unsigned short* __restrict__ out_lo,          // nullable (layer-1 h lo)
    int do_relu)
{
    __shared__ unsigned short AHs[4][64][8];      // [ks][mfma-lane][j]
    __shared__ unsigned short ALs[4][64][8];
    __shared__ unsigned short outs_hi[16][128];
    __shared__ unsigned short outs_lo[16][128];

    const int w = threadIdx.x >> 6;               // wave 0..3
    const int l = threadIdx.x & 63;
    const int tile = blockIdx.x;
    const int n0w = tile * 16;

    // ---- gather phase ----
    const int gn = l >> 2;                        // node 0..15
    const int q2 = l & 3;                         // channel sub-block
    const int gnode = n0w + gn;
    const int start = off[gnode];
    const int end   = off[gnode + 1];
    const unsigned short* fb = featbf + w * 32 + q2 * 8;

    float ga[8] = {0.f, 0.f, 0.f, 0.f, 0.f, 0.f, 0.f, 0.f};

#define ACC(rv)                                                         \
    { ga[0] += bfhi(rv.x); ga[1] += bflo(rv.x);                         \
      ga[2] += bfhi(rv.y); ga[3] += bflo(rv.y);                         \
      ga[4] += bfhi(rv.z); ga[5] += bflo(rv.z);                         \
      ga[6] += bfhi(rv.w); ga[7] += bflo(rv.w); }

    const uint4 zero4 = {0u, 0u, 0u, 0u};
    if (start < end) {
        int4 ix = *(const int4*)(csr + start);
        uint4 c0 = *(const uint4*)(fb + (size_t)ix.x * D);
        uint4 c1 = *(const uint4*)(fb + (size_t)ix.y * D);
        uint4 c2 = *(const uint4*)(fb + (size_t)ix.z * D);
        uint4 c3 = *(const uint4*)(fb + (size_t)ix.w * D);
        for (int e = start; e < end; e += 4) {
            // depth-2: issue next batch (pad-safe overshoot) before accumulating
            int4 ixn = *(const int4*)(csr + e + 4);
            uint4 n0 = *(const uint4*)(fb + (size_t)ixn.x * D);
            uint4 n1 = *(const uint4*)(fb + (size_t)ixn.y * D);
            uint4 n2 = *(const uint4*)(fb + (size_t)ixn.z * D);
            uint4 n3 = *(const uint4*)(fb + (size_t)ixn.w * D);
            if (e + 1 >= end) c1 = zero4;
            if (e + 2 >= end) c2 = zero4;
            if (e + 3 >= end) c3 = zero4;
            ACC(c0) ACC(c1) ACC(c2) ACC(c3)
            c0 = n0; c1 = n1; c2 = n2; c3 = n3;
        }
    }
#undef ACC

    // mean + bf16 hi/lo split -> LDS frag exchange
    {
        const float dinv = 1.0f / (float)max(end - start, 1);
        short8 hi8, lo8;
#pragma unroll
        for (int c = 0; c < 8; ++c) {
            float v = ga[c] * dinv;
            unsigned int hb = f2bf_bits(v);
            hi8[c] = (short)hb;
            lo8[c] = (short)f2bf_bits(v - __uint_as_float(hb << 16));
        }
        // MFMA lane (q=q2, r16=gn) consumes this as frag ks=w
        *(short8*)&AHs[w][q2 * 16 + gn][0] = hi8;
        *(short8*)&ALs[w][q2 * 16 + gn][0] = lo8;
    }
    __syncthreads();

    // ---- MFMA phase: wave w computes t = 2w, 2w+1 ----
    const int q = l >> 4, r16 = l & 15;
    const int mnode = n0w + r16;
    f32x4 acc0 = {0.f, 0.f, 0.f, 0.f};
    f32x4 acc1 = {0.f, 0.f, 0.f, 0.f};
    const unsigned short* sph = self_hi + (size_t)mnode * D + q * 8;
    const unsigned short* spl = self_lo + (size_t)mnode * D + q * 8;
    const unsigned short* bh0 = wpk_hi + (size_t)(2 * w) * 4096 + l * 8;
    const unsigned short* bl0 = wpk_lo + (size_t)(2 * w) * 4096 + l * 8;

#pragma unroll
    for (int ks = 0; ks < 8; ++ks) {
        short8 AH, AL;
        if (ks < 4) {
            AH = *(const short8*)&AHs[ks][l][0];
            AL = *(const short8*)&ALs[ks][l][0];
        } else {
            AH = *(const short8*)(sph + (ks - 4) * 32);
            AL = *(const short8*)(spl + (ks - 4) * 32);
        }
        short8 BH0 = *(const short8*)(bh0 + ks * 512);
        short8 BL0 = *(const short8*)(bl0 + ks * 512);
        short8 BH1 = *(const short8*)(bh0 + 4096 + ks * 512);
        short8 BL1 = *(const short8*)(bl0 + 4096 + ks * 512);
        acc0 = __builtin_amdgcn_mfma_f32_16x16x32_bf16(AH, BH0, acc0, 0, 0, 0);
        acc0 = __builtin_amdgcn_mfma_f32_16x16x32_bf16(AL, BH0, acc0, 0, 0, 0);
        acc0 = __builtin_amdgcn_mfma_f32_16x16x32_bf16(AH, BL0, acc0, 0, 0, 0);
        acc1 = __builtin_amdgcn_mfma_f32_16x16x32_bf16(AH, BH1, acc1, 0, 0, 0);
        acc1 = __builtin_amdgcn_mfma_f32_16x16x32_bf16(AL, BH1, acc1, 0, 0, 0);
        acc1 = __builtin_amdgcn_mfma_f32_16x16x32_bf16(AH, BL1, acc1, 0, 0, 0);
    }

    // ---- epilogue: bias/relu/split -> LDS tile -> coalesced stream ----
    {
        const float bv0 = bias[32 * w + r16];
        const float bv1 = bias[32 * w + 16 + r16];
#pragma unroll
        for (int r = 0; r < 4; ++r) {
            float v0 = acc0[r] + bv0;
            float v1 = acc1[r] + bv1;
            if (do_relu) { v0 = fmaxf(v0, 0.f); v1 = fmaxf(v1, 0.f); }
            const int row = q * 4 + r;
            unsigned int h0 = f2bf_bits(v0);
            unsigned int h1 = f2bf_bits(v1);
            outs_hi[row][32 * w + r16] = (unsigned short)h0;
            outs_hi[row][32 * w + 16 + r16] = (unsigned short)h1;
            outs_lo[row][32 * w + r16] =
                (unsigned short)f2bf_bits(v0 - __uint_as_float(h0 << 16));
            outs_lo[row][32 * w + 16 + r16] =
                (unsigned short)f2bf_bits(v1 - __uint_as_float(h1 << 16));
        }
    }
    __syncthreads();
    {
        const int tid = threadIdx.x;
        short8 vh = *(short8*)(&outs_hi[0][0] + tid * 8);
        *(short8*)(out_hi + (size_t)n0w * D + tid * 8) = vh;
        if (out_lo) {
            short8 vl = *(short8*)(&outs_lo[0][0] + tid * 8);
            *(short8*)(out_lo + (size_t)n0w * D + tid * 8) = vl;
        }
    }
}

// ---------------- edge dot-product decode (bf16 z rows) ----------------
// 32 lanes per edge, 8 B loads, reduce depth 5.
__global__ __launch_bounds__(256) void pred_kernel(const unsigned short* __restrict__ zbf,
                                                   const int* __restrict__ ps,
                                                   const int* __restrict__ pd,
                                                   float* __restrict__ out, int EP) {
    int idx = blockIdx.x * blockDim.x + threadIdx.x;
    int e = idx >> 5;
    if (e >= EP) return;
    int l = idx & 31;
    const unsigned short* fb = zbf + (size_t)l * 4;
    uint2 ra = *(const uint2*)(fb + (size_t)ps[e] * D);
    uint2 rb = *(const uint2*)(fb + (size_t)pd[e] * D);
    float p = __uint_as_float(ra.x << 16)         * __uint_as_float(rb.x << 16)
            + __uint_as_float(ra.x & 0xffff0000u) * __uint_as_float(rb.x & 0xffff0000u)
            + __uint_as_float(ra.y << 16)         * __uint_as_float(rb.y << 16)
            + __uint_as_float(ra.y & 0xffff0000u) * __uint_as_float(rb.y & 0xffff0000u);
#pragma unroll
    for (int off = 16; off > 0; off >>= 1) p += __shfl_xor(p, off, 32);
    if (l == 0) out[e] = p;
}

extern "C" void kernel_launch(void* const* d_in, const int* in_sizes, int n_in,
                              void* d_out, int out_size, void* d_ws, size_t ws_size,
                              hipStream_t stream) {
    const float* x   = (const float*)d_in[0];
    const float* W1l = (const float*)d_in[1];
    const float* b1  = (const float*)d_in[2];
    const float* W1r = (const float*)d_in[3];
    const float* W2l = (const float*)d_in[4];
    const float* b2  = (const float*)d_in[5];
    const float* W2r = (const float*)d_in[6];
    const int* edge_index = (const int*)d_in[7];
    const int* pred_edges = (const int*)d_in[8];
    float* out = (float*)d_out;

    const int N  = in_sizes[0] / D;   // 50000
    const int E  = in_sizes[7] / 2;   // 800000
    const int EP = in_sizes[8] / 2;   // 200000

    const int* src = edge_index;
    const int* dst = edge_index + E;
    const int* ps  = pred_edges;
    const int* pd  = pred_edges + EP;

    // workspace layout
    int* chist   = (int*)d_ws;                 // 256
    int* cbase   = chist + 256;                // 257 (pad 272)
    int* gcur    = cbase + 272;                // 256
    int* off     = gcur + 256;                 // N+1 (pad 50016)
    unsigned int* centries = (unsigned int*)(off + 50016);  // E
    int* csr     = (int*)(centries + E);       // E + 16 pad
    unsigned short* w1_hi = (unsigned short*)(csr + E + 16);
    unsigned short* w1_lo = w1_hi + 32768;
    unsigned short* w2_hi = w1_lo + 32768;
    unsigned short* w2_lo = w2_hi + 32768;
    unsigned short* xbf   = w2_lo + 32768;          // N*D bf16 (x hi)
    unsigned short* xlo   = xbf + (size_t)N * D;    // N*D bf16 (x lo)
    unsigned short* hbf   = xlo + (size_t)N * D;    // N*D bf16 (h hi)
    unsigned short* hlo   = hbf + (size_t)N * D;    // N*D bf16 (h lo)
    unsigned short* zbf   = hlo + (size_t)N * D;    // N*D bf16 (z)

    const int n4 = N * D / 4;
    const int ncast = (n4 + 255) / 256;             // 6250
    const int ntiles = N / 16;                      // 3125
    const int nbC = (E + CCHUNK - 1) / CCHUNK;      // 196
    const int nbD = (N + 255) / 256;                // 196
    const int nblk_pred = (EP * 32 + 255) / 256;    // 25000

    // fused prep: x hi/lo cast + weight pack + zero chist & csr pad
    prep_kernel<<<ncast + 257, 256, 0, stream>>>(x, W1l, W1r, W2l, W2r,
                                                 xbf, xlo, w1_hi, w1_lo, w2_hi, w2_lo,
                                                 n4, ncast, chist, csr + E);

    // CSR build: coarse count -> scan -> coarse multisplit -> fine bucket
    coarse_count_kernel<<<256, 256, 0, stream>>>(dst, chist, E);
    scan256_kernel<<<1, 256, 0, stream>>>(chist, cbase, gcur);
    coarse_scatter_kernel<<<nbC, 256, 0, stream>>>(src, dst, gcur, centries, E);
    fine_bucket_kernel<<<nbD, 256, 0, stream>>>(centries, cbase, off, csr, N, E);

    // layer 1: h = relu(mean(x)@W1l + x@W1r + b1) -> hbf/hlo
    fused_sage_kernel<<<ntiles, 256, 0, stream>>>(xbf, off, csr, xbf, xlo,
                                                  w1_hi, w1_lo, b1, hbf, hlo, 1);
    // layer 2: z = mean(h)@W2l + h@W2r + b2 -> zbf
    fused_sage_kernel<<<ntiles, 256, 0, stream>>>(hbf, off, csr, hbf, hlo,
                                                  w2_hi, w2_lo, b2, zbf,
                                                  (unsigned short*)nullptr, 0);
    // decode from bf16 z
    pred_kernel<<<nblk_pred, 256, 0, stream>>>(zbf, ps, pd, out, EP);
}